// Round 1
// baseline (1254.513 us; speedup 1.0000x reference)
//
#include <hip/hip_runtime.h>
#include <cstdint>
#include <cstdio>

typedef unsigned short u16;
typedef unsigned int u32;
typedef __attribute__((ext_vector_type(8))) short short8;
typedef __attribute__((ext_vector_type(4))) float f32x4;

#define E_N 8
#define T_N 1024
#define D_N 2048
#define I_N 4096

// fp32 -> bf16 round-to-nearest-even (inputs are sane, no NaN handling)
__device__ __forceinline__ u16 f2bf(float f) {
  u32 u = __builtin_bit_cast(u32, f);
  u32 r = (u + 0x7FFFu + ((u >> 16) & 1u)) >> 16;
  return (u16)r;
}

// async global->LDS, 16B per lane; LDS dest = wave-uniform base + lane*16
__device__ __forceinline__ void g2l16(const void* g, void* l) {
  __builtin_amdgcn_global_load_lds(
      (const __attribute__((address_space(1))) void*)g,
      (__attribute__((address_space(3))) void*)l, 16, 0, 0);
}

// ---------------- prepass: x fp32 -> bf16, same layout ----------------
__global__ void cvt_x_kernel(const float4* __restrict__ in, uint2* __restrict__ out, int n4) {
  int i = blockIdx.x * blockDim.x + threadIdx.x;
  if (i >= n4) return;
  float4 v = in[i];
  uint2 p;
  p.x = (u32)f2bf(v.x) | ((u32)f2bf(v.y) << 16);
  p.y = (u32)f2bf(v.z) | ((u32)f2bf(v.w) << 16);
  out[i] = p;
}

// ---- prepass: per-expert (R,C) fp32 -> (C,R) bf16 (convert + transpose) ----
__global__ void tr_cvt_kernel(const float* __restrict__ in, u16* __restrict__ out,
                              int R, int C) {
  __shared__ u16 tile[64][66];
  int e = blockIdx.z;
  const float* ine = in + (size_t)e * R * C;
  u16* oute = out + (size_t)e * R * C;
  int c0 = blockIdx.x * 64, r0 = blockIdx.y * 64;
  int tid = threadIdx.x;
  int tx = tid & 63, ty = tid >> 6;
#pragma unroll
  for (int rr = ty; rr < 64; rr += 4)
    tile[tx][rr] = f2bf(ine[(size_t)(r0 + rr) * C + c0 + tx]);
  __syncthreads();
  int tx2 = tid & 31, ty2 = tid >> 5;
#pragma unroll
  for (int cc = ty2; cc < 64; cc += 8) {
    u32 v = *(const u32*)&tile[cc][2 * tx2];
    *(u32*)&oute[(size_t)(c0 + cc) * R + r0 + 2 * tx2] = v;
  }
}

// ===========================================================================
// 4-phase-per-K-tile counted-vmcnt GEMM schedule (T3+T4+T5), BK=64 as 2x32
// LDS per operand slice: rows x 64B, chunk-XOR-swizzled (conflict-free b128)
// ===========================================================================

#define G3_PHASE(BUF, KH, RH, DOB, STAGE_STMT, GATE_STMT)                                 \
  do {                                                                                    \
    {                                                                                     \
      const u16* ap_ = (const u16*)As + aoff + (BUF) * 16384 + (KH) * 8192 + (RH) * 2048; \
      _Pragma("unroll") for (int mi_ = 0; mi_ < 4; ++mi_)                                 \
          a[mi_] = *(const short8*)(ap_ + mi_ * 512);                                     \
      if (DOB) {                                                                          \
        const u16* bp_ = (const u16*)Bs + boff + (BUF) * 16384 + (KH) * 8192;             \
        _Pragma("unroll") for (int ni_ = 0; ni_ < 4; ++ni_)                               \
            b[ni_] = *(const short8*)(bp_ + ni_ * 512);                                   \
      }                                                                                   \
    }                                                                                     \
    STAGE_STMT;                                                                           \
    __builtin_amdgcn_s_barrier();                                                         \
    asm volatile("s_waitcnt lgkmcnt(0)" ::: "memory");                                    \
    __builtin_amdgcn_sched_barrier(0);                                                    \
    __builtin_amdgcn_s_setprio(1);                                                        \
    _Pragma("unroll") for (int mi_ = 0; mi_ < 4; ++mi_)                                   \
      _Pragma("unroll") for (int ni_ = 0; ni_ < 4; ++ni_)                                 \
        acc[(RH) * 4 + mi_][ni_] = __builtin_amdgcn_mfma_f32_16x16x32_bf16(               \
            a[mi_], b[ni_], acc[(RH) * 4 + mi_][ni_], 0, 0, 0);                           \
    __builtin_amdgcn_s_setprio(0);                                                        \
    GATE_STMT;                                                                            \
    __builtin_amdgcn_s_barrier();                                                         \
  } while (0)

#define G12_PHASE(BUF, KH, RH, DOB, STAGE_STMT, GATE_STMT)                                \
  do {                                                                                    \
    {                                                                                     \
      const u16* ap_ = (const u16*)As + aoff + (BUF) * 16384 + (KH) * 8192 + (RH) * 2048; \
      _Pragma("unroll") for (int mi_ = 0; mi_ < 4; ++mi_)                                 \
          a[mi_] = *(const short8*)(ap_ + mi_ * 512);                                     \
      if (DOB) {                                                                          \
        const u16* bgp_ = (const u16*)Bg + boff + (BUF) * 8192 + (KH) * 4096;             \
        const u16* bip_ = (const u16*)Bi + boff + (BUF) * 8192 + (KH) * 4096;             \
        _Pragma("unroll") for (int ni_ = 0; ni_ < 2; ++ni_) {                             \
          bg[ni_] = *(const short8*)(bgp_ + ni_ * 512);                                   \
          bi[ni_] = *(const short8*)(bip_ + ni_ * 512);                                   \
        }                                                                                 \
      }                                                                                   \
    }                                                                                     \
    STAGE_STMT;                                                                           \
    __builtin_amdgcn_s_barrier();                                                         \
    asm volatile("s_waitcnt lgkmcnt(0)" ::: "memory");                                    \
    __builtin_amdgcn_sched_barrier(0);                                                    \
    __builtin_amdgcn_s_setprio(1);                                                        \
    _Pragma("unroll") for (int mi_ = 0; mi_ < 4; ++mi_)                                   \
      _Pragma("unroll") for (int ni_ = 0; ni_ < 2; ++ni_) {                               \
        accg[(RH) * 4 + mi_][ni_] = __builtin_amdgcn_mfma_f32_16x16x32_bf16(              \
            a[mi_], bg[ni_], accg[(RH) * 4 + mi_][ni_], 0, 0, 0);                         \
        acci[(RH) * 4 + mi_][ni_] = __builtin_amdgcn_mfma_f32_16x16x32_bf16(              \
            a[mi_], bi[ni_], acci[(RH) * 4 + mi_][ni_], 0, 0, 0);                         \
      }                                                                                   \
    __builtin_amdgcn_s_setprio(0);                                                        \
    GATE_STMT;                                                                            \
    __builtin_amdgcn_s_barrier();                                                         \
  } while (0)

// ------- fused GEMM1+2: h = silu(x@gp) * (x@ip), bf16 out, per expert -------
// BM=256, BN=128, BK=64 (2 slices of 32). 8 waves (2M x 4N), per-wave 128x32x2.
__global__ __launch_bounds__(512, 2) void gemm12_kernel(
    const u16* __restrict__ xb, const u16* __restrict__ gT,
    const u16* __restrict__ iT, u16* __restrict__ hb) {
  // [buf2][ks2][row][32 u16], 64B rows, chunk-swizzled
  __shared__ __align__(16) u16 As[32768];  // 256 rows -> 64 KiB
  __shared__ __align__(16) u16 Bg[16384];  // 128 rows -> 32 KiB
  __shared__ __align__(16) u16 Bi[16384];  // 32 KiB ; total 128 KiB

  const int TM = T_N / 256;   // 4
  const int TN = I_N / 128;   // 32
  const int PER_E = TM * TN;  // 128
  const int NWG = E_N * PER_E;

  int b0 = blockIdx.x;
  int wg = (b0 & 7) * (NWG / 8) + (b0 >> 3);  // XCD-contiguous: 1 expert/XCD
  int e = wg / PER_E;
  int r = wg % PER_E;
  int tn = r >> 2;  // tn-major: 4 consecutive tm share one B panel via L2
  int tm = r & 3;

  const u16* ae = xb + ((size_t)e * T_N + (size_t)tm * 256) * D_N;
  const u16* ge = gT + ((size_t)e * I_N + (size_t)tn * 128) * D_N;
  const u16* ie = iT + ((size_t)e * I_N + (size_t)tn * 128) * D_N;

  int tid = threadIdx.x;
  int lane = tid & 63, wid = tid >> 6;
  int wm = wid >> 2, wn = wid & 3;
  int fr = lane & 15, quad = lane >> 4;

  // staging: thread covers row=srow(+c*128), 16B chunk (tid&3); fetch the
  // XOR-permuted chunk so a LINEAR global_load_lds dest yields swizzled LDS
  int srow = tid >> 2;
  int sg = ((tid & 3) ^ ((srow >> 1) & 3)) * 8;  // pre-swizzled k-elem offset
  int csw = (quad ^ ((fr >> 1) & 3)) * 8;        // matching swizzle on read

  int aoff = (wm * 128 + fr) * 32 + csw;
  int boff = (wn * 32 + fr) * 32 + csw;

  auto stageA = [&](int kt, int ks) {
    size_t gk = (size_t)kt * 64 + ks * 32 + sg;
    char* lb = (char*)As + (size_t)((kt & 1) * 2 + ks) * 16384 + wid * 1024;
#pragma unroll
    for (int c = 0; c < 2; ++c)
      g2l16(ae + (size_t)(c * 128 + srow) * D_N + gk, lb + c * 8192);
  };
  auto stageBp = [&](int kt, int ks) {
    size_t go = (size_t)srow * D_N + (size_t)kt * 64 + ks * 32 + sg;
    size_t lo = (size_t)((kt & 1) * 2 + ks) * 8192 + wid * 1024;
    g2l16(ge + go, (char*)Bg + lo);
    g2l16(ie + go, (char*)Bi + lo);
  };

  f32x4 accg[8][2], acci[8][2];
#pragma unroll
  for (int i = 0; i < 8; ++i)
#pragma unroll
    for (int j = 0; j < 2; ++j) {
      accg[i][j] = {0.f, 0.f, 0.f, 0.f};
      acci[i][j] = {0.f, 0.f, 0.f, 0.f};
    }
  short8 a[4], bg[2], bi[2];

  // prologue: tile 0 fully; last 4 loads (slice 1) may stay in flight
  stageA(0, 0); stageBp(0, 0); stageA(0, 1); stageBp(0, 1);
  asm volatile("s_waitcnt vmcnt(4)" ::: "memory");
  __builtin_amdgcn_s_barrier();

  const int NT = D_N / 64;  // 32
  for (int t = 0; t < NT; ++t) {
    int buf = t & 1;
    bool pf = (t + 1 < NT);
    G12_PHASE(buf, 0, 0, 1, if (pf) stageA(t + 1, 0), {});
    G12_PHASE(buf, 0, 1, 0, if (pf) stageBp(t + 1, 0),
              if (pf) { asm volatile("s_waitcnt vmcnt(4)" ::: "memory"); }
              else    { asm volatile("s_waitcnt vmcnt(0)" ::: "memory"); });
    G12_PHASE(buf, 1, 0, 1, if (pf) stageA(t + 1, 1), {});
    G12_PHASE(buf, 1, 1, 0, if (pf) stageBp(t + 1, 1),
              if (pf) { asm volatile("s_waitcnt vmcnt(4)" ::: "memory"); });
  }

  // epilogue: silu(g)*u -> bf16 h.  C/D layout: col=lane&15, row=quad*4+reg
  u16* he = hb + (size_t)e * T_N * I_N;
  int orow0 = tm * 256 + wm * 128 + quad * 4;
  int ocol0 = tn * 128 + wn * 32 + fr;
#pragma unroll
  for (int mi = 0; mi < 8; ++mi)
#pragma unroll
    for (int ni = 0; ni < 2; ++ni)
#pragma unroll
      for (int rg = 0; rg < 4; ++rg) {
        float g = accg[mi][ni][rg];
        float u = acci[mi][ni][rg];
        float s = g / (1.0f + __expf(-g));
        he[(size_t)(orow0 + mi * 16 + rg) * I_N + ocol0 + ni * 16] = f2bf(s * u);
      }
}

// ---------------- GEMM3: out = h @ op, fp32 out, per expert ----------------
// BM=256, BN=256, BK=64. 8 waves (2M x 4N), per-wave 128x64.
__global__ __launch_bounds__(512, 2) void gemm3_kernel(
    const u16* __restrict__ hb, const u16* __restrict__ oT, float* __restrict__ out) {
  __shared__ __align__(16) u16 As[32768];  // 64 KiB
  __shared__ __align__(16) u16 Bs[32768];  // 64 KiB

  const int TM = T_N / 256;   // 4
  const int TN = D_N / 256;   // 8
  const int PER_E = TM * TN;  // 32
  const int NWG = E_N * PER_E;

  int b0 = blockIdx.x;
  int wg = (b0 & 7) * (NWG / 8) + (b0 >> 3);  // 1 expert per XCD
  int e = wg / PER_E;
  int r = wg % PER_E;
  int tn = r >> 2;
  int tm = r & 3;

  const u16* ae = hb + ((size_t)e * T_N + (size_t)tm * 256) * I_N;
  const u16* be = oT + ((size_t)e * D_N + (size_t)tn * 256) * I_N;

  int tid = threadIdx.x;
  int lane = tid & 63, wid = tid >> 6;
  int wm = wid >> 2, wn = wid & 3;
  int fr = lane & 15, quad = lane >> 4;

  int srow = tid >> 2;
  int sg = ((tid & 3) ^ ((srow >> 1) & 3)) * 8;
  int csw = (quad ^ ((fr >> 1) & 3)) * 8;

  int aoff = (wm * 128 + fr) * 32 + csw;
  int boff = (wn * 64 + fr) * 32 + csw;

  auto stageA = [&](int kt, int ks) {
    size_t gk = (size_t)kt * 64 + ks * 32 + sg;
    char* lb = (char*)As + (size_t)((kt & 1) * 2 + ks) * 16384 + wid * 1024;
#pragma unroll
    for (int c = 0; c < 2; ++c)
      g2l16(ae + (size_t)(c * 128 + srow) * I_N + gk, lb + c * 8192);
  };
  auto stageB = [&](int kt, int ks) {
    size_t gk = (size_t)kt * 64 + ks * 32 + sg;
    char* lb = (char*)Bs + (size_t)((kt & 1) * 2 + ks) * 16384 + wid * 1024;
#pragma unroll
    for (int c = 0; c < 2; ++c)
      g2l16(be + (size_t)(c * 128 + srow) * I_N + gk, lb + c * 8192);
  };

  f32x4 acc[8][4];
#pragma unroll
  for (int i = 0; i < 8; ++i)
#pragma unroll
    for (int j = 0; j < 4; ++j) acc[i][j] = {0.f, 0.f, 0.f, 0.f};
  short8 a[4], b[4];

  stageA(0, 0); stageB(0, 0); stageA(0, 1); stageB(0, 1);
  asm volatile("s_waitcnt vmcnt(4)" ::: "memory");
  __builtin_amdgcn_s_barrier();

  const int NT = I_N / 64;  // 64
  for (int t = 0; t < NT; ++t) {
    int buf = t & 1;
    bool pf = (t + 1 < NT);
    G3_PHASE(buf, 0, 0, 1, if (pf) stageA(t + 1, 0), {});
    G3_PHASE(buf, 0, 1, 0, if (pf) stageB(t + 1, 0),
             if (pf) { asm volatile("s_waitcnt vmcnt(4)" ::: "memory"); }
             else    { asm volatile("s_waitcnt vmcnt(0)" ::: "memory"); });
    G3_PHASE(buf, 1, 0, 1, if (pf) stageA(t + 1, 1), {});
    G3_PHASE(buf, 1, 1, 0, if (pf) stageB(t + 1, 1),
             if (pf) { asm volatile("s_waitcnt vmcnt(4)" ::: "memory"); });
  }

  float* oe = out + (size_t)e * T_N * D_N;
  int orow0 = tm * 256 + wm * 128 + quad * 4;
  int ocol0 = tn * 256 + wn * 64 + fr;
#pragma unroll
  for (int mi = 0; mi < 8; ++mi)
#pragma unroll
    for (int ni = 0; ni < 4; ++ni)
#pragma unroll
      for (int rg = 0; rg < 4; ++rg)
        oe[(size_t)(orow0 + mi * 16 + rg) * D_N + ocol0 + ni * 16] = acc[mi][ni][rg];
}

extern "C" void kernel_launch(void* const* d_in, const int* in_sizes, int n_in,
                              void* d_out, int out_size, void* d_ws, size_t ws_size,
                              hipStream_t stream) {
  const float* x = (const float*)d_in[0];
  const float* gp = (const float*)d_in[1];
  const float* ip = (const float*)d_in[2];
  const float* op = (const float*)d_in[3];
  float* out = (float*)d_out;

  const size_t szX = (size_t)E_N * T_N * D_N * 2;  // bf16 x
  const size_t szW = (size_t)E_N * D_N * I_N * 2;  // each bf16 weight (transposed)
  const size_t szH = (size_t)E_N * T_N * I_N * 2;  // bf16 h
  const size_t need = szX + 3 * szW + szH;         // 480 MiB
  if (ws_size < need) {
    fprintf(stderr, "kernel_launch: ws_size %zu < needed %zu\n", ws_size, need);
    return;
  }

  char* w = (char*)d_ws;
  u16* xb = (u16*)w; w += szX;
  u16* gT = (u16*)w; w += szW;
  u16* iT = (u16*)w; w += szW;
  u16* oTt = (u16*)w; w += szW;
  u16* hb = (u16*)w; w += szH;

  // prepass
  int n4 = E_N * T_N * D_N / 4;
  cvt_x_kernel<<<(n4 + 255) / 256, 256, 0, stream>>>((const float4*)x, (uint2*)xb, n4);
  dim3 tg1(I_N / 64, D_N / 64, E_N);  // gate/inner: (D,I) -> (I,D)
  tr_cvt_kernel<<<tg1, 256, 0, stream>>>(gp, gT, D_N, I_N);
  tr_cvt_kernel<<<tg1, 256, 0, stream>>>(ip, iT, D_N, I_N);
  dim3 tg2(D_N / 64, I_N / 64, E_N);  // op: (I,D) -> (D,I)
  tr_cvt_kernel<<<tg2, 256, 0, stream>>>(op, oTt, I_N, D_N);

  // fused GEMM1+2 -> h (bf16)
  gemm12_kernel<<<E_N * (T_N / 256) * (I_N / 128), 512, 0, stream>>>(xb, gT, iT, hb);
  // GEMM3 -> out (fp32)
  gemm3_kernel<<<E_N * (T_N / 256) * (D_N / 256), 512, 0, stream>>>(hb, oTt, out);
}

// Round 2
// 1220.626 us; speedup vs baseline: 1.0278x; 1.0278x over previous
//
#include <hip/hip_runtime.h>
#include <cstdint>
#include <cstdio>

typedef unsigned short u16;
typedef unsigned int u32;
typedef __attribute__((ext_vector_type(8))) short short8;
typedef __attribute__((ext_vector_type(4))) float f32x4;

#define E_N 8
#define T_N 1024
#define D_N 2048
#define I_N 4096

// fp32 -> bf16 round-to-nearest-even (inputs are sane, no NaN handling)
__device__ __forceinline__ u16 f2bf(float f) {
  u32 u = __builtin_bit_cast(u32, f);
  u32 r = (u + 0x7FFFu + ((u >> 16) & 1u)) >> 16;
  return (u16)r;
}

// async global->LDS, 16B per lane; LDS dest = wave-uniform base + lane*16
__device__ __forceinline__ void g2l16(const void* g, void* l) {
  __builtin_amdgcn_global_load_lds(
      (const __attribute__((address_space(1))) void*)g,
      (__attribute__((address_space(3))) void*)l, 16, 0, 0);
}

// ---------------- prepass: x fp32 -> bf16, same layout ----------------
__global__ void cvt_x_kernel(const float4* __restrict__ in, uint2* __restrict__ out, int n4) {
  int i = blockIdx.x * blockDim.x + threadIdx.x;
  if (i >= n4) return;
  float4 v = in[i];
  uint2 p;
  p.x = (u32)f2bf(v.x) | ((u32)f2bf(v.y) << 16);
  p.y = (u32)f2bf(v.z) | ((u32)f2bf(v.w) << 16);
  out[i] = p;
}

// ---- prepass: per-expert (R,C) fp32 -> (C,R) bf16 (convert + transpose) ----
// float4 loads (16B/lane), uint2 stores (8B/lane)
__global__ void tr_cvt_kernel(const float* __restrict__ in, u16* __restrict__ out,
                              int R, int C) {
  __shared__ u16 tile[64][72];  // pad 72: 8B-aligned rows, spread banks
  int e = blockIdx.z;
  const float* ine = in + (size_t)e * R * C;
  u16* oute = out + (size_t)e * R * C;
  int c0 = blockIdx.x * 64, r0 = blockIdx.y * 64;
  int tid = threadIdx.x;
  int tx = tid & 15, ty = tid >> 4;
#pragma unroll
  for (int rr = ty; rr < 64; rr += 16) {
    float4 v = *(const float4*)&ine[(size_t)(r0 + rr) * C + c0 + tx * 4];
    tile[tx * 4 + 0][rr] = f2bf(v.x);
    tile[tx * 4 + 1][rr] = f2bf(v.y);
    tile[tx * 4 + 2][rr] = f2bf(v.z);
    tile[tx * 4 + 3][rr] = f2bf(v.w);
  }
  __syncthreads();
#pragma unroll
  for (int cc = ty; cc < 64; cc += 16) {
    uint2 v = *(const uint2*)&tile[cc][tx * 4];
    *(uint2*)&oute[(size_t)(c0 + cc) * R + r0 + tx * 4] = v;
  }
}

// ===========================================================================
// 4-slot BK=32 ring schedule: stage 3 slices ahead, gate vmcnt(8) => slice
// s+1's loads were issued ~4 phases earlier (covers ~900cy HBM latency).
// LDS rows = 64B, chunk-XOR-swizzled (conflict-free ds_read_b128).
// ===========================================================================

#define G3_PHASE(SLOT, RH, DOB, STAGE_STMT, GATE_STMT)                                 \
  do {                                                                                 \
    {                                                                                  \
      const u16* ap_ = (const u16*)As + aoff + (SLOT) * 8192 + (RH) * 2048;            \
      _Pragma("unroll") for (int mi_ = 0; mi_ < 4; ++mi_)                              \
          a[mi_] = *(const short8*)(ap_ + mi_ * 512);                                  \
      if (DOB) {                                                                       \
        const u16* bp_ = (const u16*)Bs + boff + (SLOT) * 8192;                        \
        _Pragma("unroll") for (int ni_ = 0; ni_ < 4; ++ni_)                            \
            b[ni_] = *(const short8*)(bp_ + ni_ * 512);                                \
      }                                                                                \
    }                                                                                  \
    STAGE_STMT;                                                                        \
    __builtin_amdgcn_s_barrier();                                                      \
    asm volatile("s_waitcnt lgkmcnt(0)" ::: "memory");                                 \
    __builtin_amdgcn_sched_barrier(0);                                                 \
    __builtin_amdgcn_s_setprio(1);                                                     \
    _Pragma("unroll") for (int mi_ = 0; mi_ < 4; ++mi_)                                \
      _Pragma("unroll") for (int ni_ = 0; ni_ < 4; ++ni_)                              \
        acc[(RH) * 4 + mi_][ni_] = __builtin_amdgcn_mfma_f32_16x16x32_bf16(            \
            a[mi_], b[ni_], acc[(RH) * 4 + mi_][ni_], 0, 0, 0);                        \
    __builtin_amdgcn_s_setprio(0);                                                     \
    GATE_STMT;                                                                         \
    __builtin_amdgcn_s_barrier();                                                      \
  } while (0)

#define G12_PHASE(SLOT, RH, DOB, STAGE_STMT, GATE_STMT)                                \
  do {                                                                                 \
    {                                                                                  \
      const u16* ap_ = (const u16*)As + aoff + (SLOT) * 8192 + (RH) * 2048;            \
      _Pragma("unroll") for (int mi_ = 0; mi_ < 4; ++mi_)                              \
          a[mi_] = *(const short8*)(ap_ + mi_ * 512);                                  \
      if (DOB) {                                                                       \
        const u16* bgp_ = (const u16*)Bg + boff + (SLOT) * 4096;                       \
        const u16* bip_ = (const u16*)Bi + boff + (SLOT) * 4096;                       \
        _Pragma("unroll") for (int ni_ = 0; ni_ < 2; ++ni_) {                          \
          bg[ni_] = *(const short8*)(bgp_ + ni_ * 512);                                \
          bi[ni_] = *(const short8*)(bip_ + ni_ * 512);                                \
        }                                                                              \
      }                                                                                \
    }                                                                                  \
    STAGE_STMT;                                                                        \
    __builtin_amdgcn_s_barrier();                                                      \
    asm volatile("s_waitcnt lgkmcnt(0)" ::: "memory");                                 \
    __builtin_amdgcn_sched_barrier(0);                                                 \
    __builtin_amdgcn_s_setprio(1);                                                     \
    _Pragma("unroll") for (int mi_ = 0; mi_ < 4; ++mi_)                                \
      _Pragma("unroll") for (int ni_ = 0; ni_ < 2; ++ni_) {                            \
        accg[(RH) * 4 + mi_][ni_] = __builtin_amdgcn_mfma_f32_16x16x32_bf16(           \
            a[mi_], bg[ni_], accg[(RH) * 4 + mi_][ni_], 0, 0, 0);                      \
        acci[(RH) * 4 + mi_][ni_] = __builtin_amdgcn_mfma_f32_16x16x32_bf16(           \
            a[mi_], bi[ni_], acci[(RH) * 4 + mi_][ni_], 0, 0, 0);                      \
      }                                                                                \
    __builtin_amdgcn_s_setprio(0);                                                     \
    GATE_STMT;                                                                         \
    __builtin_amdgcn_s_barrier();                                                      \
  } while (0)

// ------- fused GEMM1+2: h = silu(x@gp) * (x@ip), bf16 out, per expert -------
// BM=256, BN=128, ring of 4 BK=32 slices. 8 waves (2M x 4N).
__global__ __launch_bounds__(512, 2) void gemm12_kernel(
    const u16* __restrict__ xb, const u16* __restrict__ gT,
    const u16* __restrict__ iT, u16* __restrict__ hb) {
  __shared__ __align__(16) u16 As[32768];  // 4 slots x 256 rows x 32 -> 64 KiB
  __shared__ __align__(16) u16 Bg[16384];  // 4 slots x 128 rows x 32 -> 32 KiB
  __shared__ __align__(16) u16 Bi[16384];  // 32 KiB ; total 128 KiB

  const int TM = T_N / 256;   // 4
  const int TN = I_N / 128;   // 32
  const int PER_E = TM * TN;  // 128
  const int NWG = E_N * PER_E;

  int b0 = blockIdx.x;
  int wg = (b0 & 7) * (NWG / 8) + (b0 >> 3);  // XCD-contiguous: 1 expert/XCD
  int e = wg / PER_E;
  int r = wg % PER_E;
  int tn = r >> 2;  // tn-major: 4 consecutive tm share one B panel via L2
  int tm = r & 3;

  const u16* ae = xb + ((size_t)e * T_N + (size_t)tm * 256) * D_N;
  const u16* ge = gT + ((size_t)e * I_N + (size_t)tn * 128) * D_N;
  const u16* ie = iT + ((size_t)e * I_N + (size_t)tn * 128) * D_N;

  int tid = threadIdx.x;
  int lane = tid & 63, wid = tid >> 6;
  int wm = wid >> 2, wn = wid & 3;
  int fr = lane & 15, quad = lane >> 4;

  // staging: thread covers row=srow(+c*128), 16B chunk (tid&3); fetch the
  // XOR-permuted chunk so a LINEAR global_load_lds dest yields swizzled LDS
  int srow = tid >> 2;
  int sg = ((tid & 3) ^ ((srow >> 1) & 3)) * 8;  // pre-swizzled k-elem offset
  int csw = (quad ^ ((fr >> 1) & 3)) * 8;        // matching swizzle on read

  int aoff = (wm * 128 + fr) * 32 + csw;
  int boff = (wn * 32 + fr) * 32 + csw;

  auto stageA = [&](int s) {
    size_t gk = (size_t)s * 32 + sg;
    char* lb = (char*)As + (size_t)(s & 3) * 16384 + wid * 1024;
#pragma unroll
    for (int c = 0; c < 2; ++c)
      g2l16(ae + (size_t)(c * 128 + srow) * D_N + gk, lb + c * 8192);
  };
  auto stageBp = [&](int s) {
    size_t go = (size_t)srow * D_N + (size_t)s * 32 + sg;
    size_t lo = (size_t)(s & 3) * 8192 + wid * 1024;
    g2l16(ge + go, (char*)Bg + lo);
    g2l16(ie + go, (char*)Bi + lo);
  };

  f32x4 accg[8][2], acci[8][2];
#pragma unroll
  for (int i = 0; i < 8; ++i)
#pragma unroll
    for (int j = 0; j < 2; ++j) {
      accg[i][j] = {0.f, 0.f, 0.f, 0.f};
      acci[i][j] = {0.f, 0.f, 0.f, 0.f};
    }
  short8 a[4], bg[2], bi[2];

  // prologue: stage slices 0..2 (12 loads); wait slice 0 (all but newest 8)
  stageA(0); stageBp(0); stageA(1); stageBp(1); stageA(2); stageBp(2);
  asm volatile("s_waitcnt vmcnt(8)" ::: "memory");
  __builtin_amdgcn_s_barrier();

  const int NS = D_N / 32;  // 64
  for (int s = 0; s < NS; ++s) {
    int slot = s & 3;
    bool pf = (s + 3 < NS);
    G12_PHASE(slot, 0, 1, if (pf) stageA(s + 3), {});
    G12_PHASE(slot, 1, 0, if (pf) stageBp(s + 3),
              if (s + 3 < NS)      { asm volatile("s_waitcnt vmcnt(8)" ::: "memory"); }
              else if (s + 2 < NS) { asm volatile("s_waitcnt vmcnt(4)" ::: "memory"); }
              else if (s + 1 < NS) { asm volatile("s_waitcnt vmcnt(0)" ::: "memory"); });
  }

  // epilogue: silu(g)*u -> bf16 h.  C/D layout: col=lane&15, row=quad*4+reg
  u16* he = hb + (size_t)e * T_N * I_N;
  int orow0 = tm * 256 + wm * 128 + quad * 4;
  int ocol0 = tn * 128 + wn * 32 + fr;
#pragma unroll
  for (int mi = 0; mi < 8; ++mi)
#pragma unroll
    for (int ni = 0; ni < 2; ++ni)
#pragma unroll
      for (int rg = 0; rg < 4; ++rg) {
        float g = accg[mi][ni][rg];
        float u = acci[mi][ni][rg];
        float s = g / (1.0f + __expf(-g));
        he[(size_t)(orow0 + mi * 16 + rg) * I_N + ocol0 + ni * 16] = f2bf(s * u);
      }
}

// ---------------- GEMM3: out = h @ op, fp32 out, per expert ----------------
// BM=256, BN=256, ring of 4 BK=32 slices. 8 waves (2M x 4N).
__global__ __launch_bounds__(512, 2) void gemm3_kernel(
    const u16* __restrict__ hb, const u16* __restrict__ oT, float* __restrict__ out) {
  __shared__ __align__(16) u16 As[32768];  // 4 slots x 256 rows x 32 -> 64 KiB
  __shared__ __align__(16) u16 Bs[32768];  // 64 KiB

  const int TM = T_N / 256;   // 4
  const int TN = D_N / 256;   // 8
  const int PER_E = TM * TN;  // 32
  const int NWG = E_N * PER_E;

  int b0 = blockIdx.x;
  int wg = (b0 & 7) * (NWG / 8) + (b0 >> 3);  // 1 expert per XCD
  int e = wg / PER_E;
  int r = wg % PER_E;
  int tn = r >> 2;
  int tm = r & 3;

  const u16* ae = hb + ((size_t)e * T_N + (size_t)tm * 256) * I_N;
  const u16* be = oT + ((size_t)e * D_N + (size_t)tn * 256) * I_N;

  int tid = threadIdx.x;
  int lane = tid & 63, wid = tid >> 6;
  int wm = wid >> 2, wn = wid & 3;
  int fr = lane & 15, quad = lane >> 4;

  int srow = tid >> 2;
  int sg = ((tid & 3) ^ ((srow >> 1) & 3)) * 8;
  int csw = (quad ^ ((fr >> 1) & 3)) * 8;

  int aoff = (wm * 128 + fr) * 32 + csw;
  int boff = (wn * 64 + fr) * 32 + csw;

  auto stageA = [&](int s) {
    size_t gk = (size_t)s * 32 + sg;
    char* lb = (char*)As + (size_t)(s & 3) * 16384 + wid * 1024;
#pragma unroll
    for (int c = 0; c < 2; ++c)
      g2l16(ae + (size_t)(c * 128 + srow) * I_N + gk, lb + c * 8192);
  };
  auto stageB = [&](int s) {
    size_t gk = (size_t)s * 32 + sg;
    char* lb = (char*)Bs + (size_t)(s & 3) * 16384 + wid * 1024;
#pragma unroll
    for (int c = 0; c < 2; ++c)
      g2l16(be + (size_t)(c * 128 + srow) * I_N + gk, lb + c * 8192);
  };

  f32x4 acc[8][4];
#pragma unroll
  for (int i = 0; i < 8; ++i)
#pragma unroll
    for (int j = 0; j < 4; ++j) acc[i][j] = {0.f, 0.f, 0.f, 0.f};
  short8 a[4], b[4];

  stageA(0); stageB(0); stageA(1); stageB(1); stageA(2); stageB(2);
  asm volatile("s_waitcnt vmcnt(8)" ::: "memory");
  __builtin_amdgcn_s_barrier();

  const int NS = I_N / 32;  // 128
  for (int s = 0; s < NS; ++s) {
    int slot = s & 3;
    bool pf = (s + 3 < NS);
    G3_PHASE(slot, 0, 1, if (pf) stageA(s + 3), {});
    G3_PHASE(slot, 1, 0, if (pf) stageB(s + 3),
             if (s + 3 < NS)      { asm volatile("s_waitcnt vmcnt(8)" ::: "memory"); }
             else if (s + 2 < NS) { asm volatile("s_waitcnt vmcnt(4)" ::: "memory"); }
             else if (s + 1 < NS) { asm volatile("s_waitcnt vmcnt(0)" ::: "memory"); });
  }

  float* oe = out + (size_t)e * T_N * D_N;
  int orow0 = tm * 256 + wm * 128 + quad * 4;
  int ocol0 = tn * 256 + wn * 64 + fr;
#pragma unroll
  for (int mi = 0; mi < 8; ++mi)
#pragma unroll
    for (int ni = 0; ni < 4; ++ni)
#pragma unroll
      for (int rg = 0; rg < 4; ++rg)
        oe[(size_t)(orow0 + mi * 16 + rg) * D_N + ocol0 + ni * 16] = acc[mi][ni][rg];
}

extern "C" void kernel_launch(void* const* d_in, const int* in_sizes, int n_in,
                              void* d_out, int out_size, void* d_ws, size_t ws_size,
                              hipStream_t stream) {
  const float* x = (const float*)d_in[0];
  const float* gp = (const float*)d_in[1];
  const float* ip = (const float*)d_in[2];
  const float* op = (const float*)d_in[3];
  float* out = (float*)d_out;

  const size_t szX = (size_t)E_N * T_N * D_N * 2;  // bf16 x
  const size_t szW = (size_t)E_N * D_N * I_N * 2;  // each bf16 weight (transposed)
  const size_t szH = (size_t)E_N * T_N * I_N * 2;  // bf16 h
  const size_t need = szX + 3 * szW + szH;         // 480 MiB
  if (ws_size < need) {
    fprintf(stderr, "kernel_launch: ws_size %zu < needed %zu\n", ws_size, need);
    return;
  }

  char* w = (char*)d_ws;
  u16* xb = (u16*)w; w += szX;
  u16* gT = (u16*)w; w += szW;
  u16* iT = (u16*)w; w += szW;
  u16* oTt = (u16*)w; w += szW;
  u16* hb = (u16*)w; w += szH;

  // prepass
  int n4 = E_N * T_N * D_N / 4;
  cvt_x_kernel<<<(n4 + 255) / 256, 256, 0, stream>>>((const float4*)x, (uint2*)xb, n4);
  dim3 tg1(I_N / 64, D_N / 64, E_N);  // gate/inner: (D,I) -> (I,D)
  tr_cvt_kernel<<<tg1, 256, 0, stream>>>(gp, gT, D_N, I_N);
  tr_cvt_kernel<<<tg1, 256, 0, stream>>>(ip, iT, D_N, I_N);
  dim3 tg2(D_N / 64, I_N / 64, E_N);  // op: (I,D) -> (D,I)
  tr_cvt_kernel<<<tg2, 256, 0, stream>>>(op, oTt, I_N, D_N);

  // fused GEMM1+2 -> h (bf16)
  gemm12_kernel<<<E_N * (T_N / 256) * (I_N / 128), 512, 0, stream>>>(xb, gT, iT, hb);
  // GEMM3 -> out (fp32)
  gemm3_kernel<<<E_N * (T_N / 256) * (D_N / 256), 512, 0, stream>>>(hb, oTt, out);
}